// Round 1
// baseline (39899.210 us; speedup 1.0000x reference)
//
#include <hip/hip_runtime.h>
#include <math.h>

#define NI 64
#define NO 64
#define NH 512
#define NM 64
#define NN 128
#define NB 32
#define NS 256
#define CTRL 640   // NI + NM + NH
#define ZD 2048    // 4*NH
#define PD 268     // R_SZ + W_SZ

__device__ __forceinline__ float sigm(float x){ return 1.0f/(1.0f+expf(-x)); }
__device__ __forceinline__ float softplus_(float x){ return (x>15.f)? x : log1pf(expf(x)); }

// content+location addressing for one head. scal = [knorm, beta, g, s0, s1, s2, gamma]
__device__ void address_head(int tid, const float* __restrict__ k_s,
                             const float* __restrict__ scal,
                             float* __restrict__ w_arr,
                             const float* __restrict__ mem_s,
                             float* __restrict__ sim_s)
{
  // phase 1: cosine similarity, all 1024 threads, 8 threads per memory row
  {
    int n = tid >> 3, sub = tid & 7;
    const float* row = mem_s + n*NM + sub*8;
    const float* kk  = k_s + sub*8;
    float dot = 0.f, sq = 0.f;
#pragma unroll
    for (int i=0;i<8;++i){ float mv = row[i]; dot = fmaf(kk[i], mv, dot); sq = fmaf(mv, mv, sq); }
#pragma unroll
    for (int off=1; off<8; off<<=1){ dot += __shfl_xor(dot, off); sq += __shfl_xor(sq, off); }
    if (sub == 0) sim_s[n] = dot / (scal[0]*sqrtf(sq) + 1e-8f);
  }
  __syncthreads();
  // phase 2: softmax + gate + circular shift + sharpen, wave 0 only (lane l owns rows l and l+64)
  if (tid < 64) {
    int l = tid;
    float beta = scal[1], g = scal[2], s0 = scal[3], s1 = scal[4], s2 = scal[5], gamma = scal[6];
    float x0 = beta*sim_s[l], x1 = beta*sim_s[l+64];
    float mx = fmaxf(x0, x1);
#pragma unroll
    for (int off=32; off; off>>=1) mx = fmaxf(mx, __shfl_xor(mx, off));
    float e0 = expf(x0-mx), e1 = expf(x1-mx);
    float sm = e0+e1;
#pragma unroll
    for (int off=32; off; off>>=1) sm += __shfl_xor(sm, off);
    float inv = 1.0f/sm;
    float wg0 = g*e0*inv + (1.f-g)*w_arr[l];
    float wg1 = g*e1*inv + (1.f-g)*w_arr[l+64];
    // circular neighbors across the 2-rows-per-lane layout (8 shuffles, no LDS round-trip)
    float up0 = __shfl(wg0, (l+1)&63);
    float w1f = __shfl(wg1, 0);
    float plus0 = (l==63) ? w1f : up0;          // wg[(l+1) mod 128]
    float dn0 = __shfl(wg0, (l-1)&63);
    float w1b = __shfl(wg1, 63);
    float minus0 = (l==0) ? w1b : dn0;          // wg[(l-1) mod 128]
    float up1 = __shfl(wg1, (l+1)&63);
    float w0f = __shfl(wg0, 0);
    float plus1 = (l==63) ? w0f : up1;          // wg[(64+l+1) mod 128]
    float dn1 = __shfl(wg1, (l-1)&63);
    float w0b = __shfl(wg0, 63);
    float minus1 = (l==0) ? w0b : dn1;          // wg[(64+l-1) mod 128]
    // ws[n] = s0*wg[n+1] + s1*wg[n] + s2*wg[n-1]
    float ws0 = s0*plus0 + s1*wg0 + s2*minus0;
    float ws1 = s0*plus1 + s1*wg1 + s2*minus1;
    float wp0 = powf(fmaxf(ws0, 1e-12f), gamma);
    float wp1 = powf(fmaxf(ws1, 1e-12f), gamma);
    float tot = wp0+wp1;
#pragma unroll
    for (int off=32; off; off>>=1) tot += __shfl_xor(tot, off);
    float invt = 1.0f/tot;
    w_arr[l]    = wp0*invt;
    w_arr[l+64] = wp1*invt;
  }
  __syncthreads();
}

extern "C" __global__ __launch_bounds__(1024, 1)
void ntm_kernel(const float* __restrict__ inputs,
                const float* __restrict__ W_lstm,
                const float* __restrict__ b_lstm,
                const float* __restrict__ W_int,
                const float* __restrict__ b_int,
                const float* __restrict__ W_out,
                const float* __restrict__ b_out,
                float* __restrict__ out)
{
  __shared__ float mem_s[NN*NM];     // 32 KB memory matrix
  __shared__ float in_s[CTRL];
  __shared__ float zp_s[2][ZD];      // k-split partial sums of LSTM GEMV
  __shared__ float h_s[NH];
  __shared__ float c_s[NH];
  __shared__ float r_s[NM];
  __shared__ float wr_s[NN];
  __shared__ float ww_s[NN];
  __shared__ float pp_s[2][PD];
  __shared__ float p_s[PD];
  __shared__ float rk_s[NM], wk_s[NM], e_s[NM], a_s[NM];
  __shared__ float sim_s[NN];
  __shared__ float red_s[16][NO];
  __shared__ float scal_s[14];       // [0..6] read head, [7..13] write head

  const int tid = threadIdx.x;
  const int b   = blockIdx.x;

  // initial state
  for (int i = tid; i < NN*NM; i += 1024) mem_s[i] = 0.01f;
  if (tid < NH) { h_s[tid] = 0.f; c_s[tid] = 0.f; }
  if (tid < NM) r_s[tid] = 0.01f;
  if (tid < NN) { wr_s[tid] = (tid==0)?1.f:0.f; ww_s[tid] = (tid==0)?1.f:0.f; }
  __syncthreads();

  const int kg = tid >> 9;       // k-half: 0 or 1
  const int q  = tid & 511;      // column quad: cols 4q..4q+3
  const float* Wl_base = W_lstm + (size_t)(kg*320)*ZD + 4*q;

  for (int step = 0; step < NS; ++step) {
    // A: controller input = [x_t, r, h]
    if (tid < CTRL) {
      float v;
      if (tid < NI)          v = inputs[(size_t)b*NS*NI + (size_t)step*NI + tid];
      else if (tid < NI+NM)  v = r_s[tid-NI];
      else                   v = h_s[tid-NI-NM];
      in_s[tid] = v;
    }
    __syncthreads();

    // B: z = in @ W_lstm (each thread: 4 cols via float4, k split in halves)
    {
      float4 acc = make_float4(0.f,0.f,0.f,0.f);
      const float* wp = Wl_base;
      const int kbase = kg*320;
#pragma unroll 8
      for (int kk = 0; kk < 320; ++kk) {
        float xv = in_s[kbase+kk];
        float4 w = *(const float4*)(wp);
        wp += ZD;
        acc.x = fmaf(xv, w.x, acc.x);
        acc.y = fmaf(xv, w.y, acc.y);
        acc.z = fmaf(xv, w.z, acc.z);
        acc.w = fmaf(xv, w.w, acc.w);
      }
      *(float4*)&zp_s[kg][4*q] = acc;
    }
    __syncthreads();

    // C: LSTM gates (i, f, g, o)
    if (tid < NH) {
      float zi = zp_s[0][tid]      + zp_s[1][tid]      + b_lstm[tid];
      float zf = zp_s[0][NH+tid]   + zp_s[1][NH+tid]   + b_lstm[NH+tid];
      float zg = zp_s[0][2*NH+tid] + zp_s[1][2*NH+tid] + b_lstm[2*NH+tid];
      float zo = zp_s[0][3*NH+tid] + zp_s[1][3*NH+tid] + b_lstm[3*NH+tid];
      float c = sigm(zf)*c_s[tid] + sigm(zi)*tanhf(zg);
      c_s[tid] = c;
      h_s[tid] = sigm(zo)*tanhf(c);
    }
    __syncthreads();

    // D: p = h @ W_int + b_int (268 cols, 2 k-halves)
    if (tid < 2*PD) {
      int half = (tid >= PD) ? 1 : 0;
      int col  = tid - half*PD;
      int kb = half*256;
      float acc = 0.f;
#pragma unroll 8
      for (int k = 0; k < 256; ++k)
        acc = fmaf(h_s[kb+k], W_int[(size_t)(kb+k)*PD + col], acc);
      pp_s[half][col] = acc;
    }
    __syncthreads();
    if (tid < PD) p_s[tid] = pp_s[0][tid] + pp_s[1][tid] + b_int[tid];
    __syncthreads();

    // E: head parameters
    if (tid < NM) {
      float rk = tanhf(p_s[tid]);
      float wk = tanhf(p_s[70+tid]);
      rk_s[tid] = rk; wk_s[tid] = wk;
      e_s[tid] = sigm(p_s[140+tid]);
      a_s[tid] = tanhf(p_s[204+tid]);
      float sr = rk*rk, sw = wk*wk;
#pragma unroll
      for (int off=32; off; off>>=1){ sr += __shfl_xor(sr,off); sw += __shfl_xor(sw,off); }
      if (tid == 0) { scal_s[0] = sqrtf(sr); scal_s[7] = sqrtf(sw); }
    }
    if (tid == 64) {      // read-head scalars (wave 1, runs alongside wave 0)
      scal_s[1] = softplus_(p_s[64]);
      scal_s[2] = sigm(p_s[65]);
      float a0=p_s[66], a1=p_s[67], a2=p_s[68];
      float m = fmaxf(a0,fmaxf(a1,a2));
      float e0=expf(a0-m), e1=expf(a1-m), e2=expf(a2-m);
      float s = e0+e1+e2;
      scal_s[3]=e0/s; scal_s[4]=e1/s; scal_s[5]=e2/s;
      scal_s[6] = 1.f + softplus_(p_s[69]);
    }
    if (tid == 128) {     // write-head scalars (wave 2)
      scal_s[8]  = softplus_(p_s[134]);
      scal_s[9]  = sigm(p_s[135]);
      float a0=p_s[136], a1=p_s[137], a2=p_s[138];
      float m = fmaxf(a0,fmaxf(a1,a2));
      float e0=expf(a0-m), e1=expf(a1-m), e2=expf(a2-m);
      float s = e0+e1+e2;
      scal_s[10]=e0/s; scal_s[11]=e1/s; scal_s[12]=e2/s;
      scal_s[13] = 1.f + softplus_(p_s[139]);
    }
    __syncthreads();

    // F: write-head addressing (uses OLD memory, updates ww_s in place)
    address_head(tid, wk_s, &scal_s[7], ww_s, mem_s, sim_s);

    // G: memory erase+add
    {
      int n = tid >> 3, m0 = (tid & 7) * 8;
      float w = ww_s[n];
      float* row = mem_s + n*NM + m0;
#pragma unroll
      for (int i=0;i<8;++i) {
        float mv = row[i];
        row[i] = mv * (1.f - w*e_s[m0+i]) + w*a_s[m0+i];
      }
    }
    __syncthreads();

    // H: read-head addressing on updated memory
    address_head(tid, rk_s, &scal_s[0], wr_s, mem_s, sim_s);

    // I: r = w_r @ mem
    if (tid < 512) {
      int m = tid & 63, part = tid >> 6;   // 8 parts x 16 rows
      float acc = 0.f;
#pragma unroll
      for (int nn=0; nn<16; ++nn) {
        int n = part*16+nn;
        acc = fmaf(wr_s[n], mem_s[n*NM+m], acc);
      }
      red_s[part][m] = acc;
    }
    __syncthreads();
    if (tid < NM) {
      float acc = 0.f;
#pragma unroll
      for (int pqq=0; pqq<8; ++pqq) acc += red_s[pqq][tid];
      r_s[tid] = acc;
    }
    __syncthreads();

    // J: out = [h, r] @ W_out + b_out (64 cols, 16 k-parts of 36)
    {
      int col = tid & 63, part = tid >> 6;
      float acc = 0.f;
      int k0 = part*36;
#pragma unroll
      for (int kk=0; kk<36; ++kk) {
        int k = k0+kk;
        float v = (k < NH) ? h_s[k] : r_s[k-NH];
        acc = fmaf(v, W_out[(size_t)k*NO + col], acc);
      }
      red_s[part][col] = acc;
    }
    __syncthreads();
    if (tid < NO) {
      float acc = b_out[tid];
#pragma unroll
      for (int pqq=0; pqq<16; ++pqq) acc += red_s[pqq][tid];
      out[(size_t)b*NS*NO + (size_t)step*NO + tid] = acc;
    }
    __syncthreads();
  }
}

extern "C" void kernel_launch(void* const* d_in, const int* in_sizes, int n_in,
                              void* d_out, int out_size, void* d_ws, size_t ws_size,
                              hipStream_t stream) {
  const float* inputs = (const float*)d_in[0];
  const float* W_lstm = (const float*)d_in[1];
  const float* b_lstm = (const float*)d_in[2];
  const float* W_int  = (const float*)d_in[3];
  const float* b_int  = (const float*)d_in[4];
  const float* W_out  = (const float*)d_in[5];
  const float* b_out  = (const float*)d_in[6];
  hipLaunchKernelGGL(ntm_kernel, dim3(NB), dim3(1024), 0, stream,
                     inputs, W_lstm, b_lstm, W_int, b_int, W_out, b_out,
                     (float*)d_out);
}

// Round 2
// 14586.566 us; speedup vs baseline: 2.7353x; 2.7353x over previous
//
#include <hip/hip_runtime.h>
#include <hip/hip_cooperative_groups.h>
#include <math.h>

namespace cg = cooperative_groups;

#define NI 64
#define NO 64
#define NH 512
#define NM 64
#define NN 128
#define NB 32
#define NS 256
#define ZD 2048
#define PD 268
#define GBLK 64
#define TPB 256
#define JP 8          // hidden units per block (64 blocks * 8 = 512)

__device__ __forceinline__ float sigm(float x){ return 1.0f/(1.0f+expf(-x)); }
__device__ __forceinline__ float softplus_(float x){ return (x>15.f)? x : log1pf(expf(x)); }

// content+location addressing; 256 threads; mem_s is XOR-swizzled: logical
// mem[n][m] stored at float offset n*64 + (m ^ ((n&7)<<2)).
__device__ void address_head2(int t, const float* __restrict__ ks,
                              const float* __restrict__ scal,
                              float* __restrict__ w_arr,
                              const float* __restrict__ mem_s,
                              float* __restrict__ sim_s)
{
  {
    int n = t >> 1, sub = t & 1;
    int cn = (n & 7) << 2;
    const float* kk = ks + sub*32;
    float dot = 0.f, sq = 0.f;
#pragma unroll
    for (int i = 0; i < 32; i += 4) {
      int m = sub*32 + i;
      float4 mv = *(const float4*)&mem_s[n*NM + (m ^ cn)];
      float4 kv = *(const float4*)&kk[i];
      dot = fmaf(kv.x, mv.x, dot); dot = fmaf(kv.y, mv.y, dot);
      dot = fmaf(kv.z, mv.z, dot); dot = fmaf(kv.w, mv.w, dot);
      sq  = fmaf(mv.x, mv.x, sq);  sq  = fmaf(mv.y, mv.y, sq);
      sq  = fmaf(mv.z, mv.z, sq);  sq  = fmaf(mv.w, mv.w, sq);
    }
    dot += __shfl_xor(dot, 1); sq += __shfl_xor(sq, 1);
    if (sub == 0) sim_s[n] = dot / (scal[0]*sqrtf(sq) + 1e-8f);
  }
  __syncthreads();
  if (t < 64) {   // wave 0: softmax + gate + circular shift + sharpen (lane l owns rows l, l+64)
    int l = t;
    float beta = scal[1], g = scal[2], s0 = scal[3], s1 = scal[4], s2 = scal[5], gamma = scal[6];
    float x0 = beta*sim_s[l], x1 = beta*sim_s[l+64];
    float mx = fmaxf(x0, x1);
#pragma unroll
    for (int off=32; off; off>>=1) mx = fmaxf(mx, __shfl_xor(mx, off));
    float e0 = expf(x0-mx), e1 = expf(x1-mx);
    float sm = e0+e1;
#pragma unroll
    for (int off=32; off; off>>=1) sm += __shfl_xor(sm, off);
    float inv = 1.0f/sm;
    float wg0 = g*e0*inv + (1.f-g)*w_arr[l];
    float wg1 = g*e1*inv + (1.f-g)*w_arr[l+64];
    float up0 = __shfl(wg0, (l+1)&63);
    float w1f = __shfl(wg1, 0);
    float plus0 = (l==63) ? w1f : up0;
    float dn0 = __shfl(wg0, (l-1)&63);
    float w1b = __shfl(wg1, 63);
    float minus0 = (l==0) ? w1b : dn0;
    float up1 = __shfl(wg1, (l+1)&63);
    float w0f = __shfl(wg0, 0);
    float plus1 = (l==63) ? w0f : up1;
    float dn1 = __shfl(wg1, (l-1)&63);
    float w0b = __shfl(wg0, 63);
    float minus1 = (l==0) ? w0b : dn1;
    float ws0 = s0*plus0 + s1*wg0 + s2*minus0;
    float ws1 = s0*plus1 + s1*wg1 + s2*minus1;
    float wp0 = powf(fmaxf(ws0, 1e-12f), gamma);
    float wp1 = powf(fmaxf(ws1, 1e-12f), gamma);
    float tot = wp0+wp1;
#pragma unroll
    for (int off=32; off; off>>=1) tot += __shfl_xor(tot, off);
    float invt = 1.0f/tot;
    w_arr[l]    = wp0*invt;
    w_arr[l+64] = wp1*invt;
  }
  __syncthreads();
}

extern "C" __global__ __launch_bounds__(TPB, 1)
void ntm_coop(const float* __restrict__ inputs, const float* __restrict__ W_lstm,
              const float* __restrict__ b_lstm, const float* __restrict__ W_int,
              const float* __restrict__ b_int, const float* __restrict__ W_out,
              const float* __restrict__ b_out, float* __restrict__ out,
              float* __restrict__ ws)
{
  cg::grid_group grid = cg::this_grid();

  __shared__ float mem_s[NN*NM];          // 32 KB, persistent (batch blocks)
  __shared__ float wr_s[NN], ww_s[NN];    // persistent weightings
  __shared__ float inT_s[64*32];          // P1: staged [k][b] chunk
  __shared__ float zpart[4*32*32];        // P1: k-split partials
  __shared__ float h_s[NH];
  __shared__ float p_s[PD];
  __shared__ float rk_s[NM], wk_s[NM], e_s[NM], a_s[NM];
  __shared__ float sim_s[NN];
  __shared__ float red_s[4*64];
  __shared__ float r_s[NM];
  __shared__ float scal_s[14];

  float* hT0 = ws;                 // [512][32]
  float* hT1 = ws + NH*NB;
  float* rT  = ws + 2*NH*NB;       // [64][32]

  const int t = threadIdx.x;
  const int g = blockIdx.x;
  const bool isB = (g < NB);
  const int b = g;

  // LSTM pointwise ownership: (jj, b) persistent cell state in register
  const int pj = t >> 5;           // 0..7
  const int pb = t & 31;           // 0..31
  const int j0 = g * JP;
  float c_reg = 0.f;

  // P1 compute decode: wave = k-part, then 8 col-groups x 8 batch-groups
  const int kp = t >> 6;           // 0..3
  const int r6 = t & 63;
  const int cg_ = r6 >> 3;         // 0..7
  const int bg = r6 & 7;           // 0..7
  const int b0 = bg * 4;
  const int gate = cg_ >> 1;       // 0..3
  const int jj4 = (cg_ & 1) * 4;   // 0 or 4
  const int colg = gate*NH + j0 + jj4;

  if (isB) {
    for (int i = t; i < NN*NM; i += TPB) mem_s[i] = 0.01f;
    if (t < NN) { wr_s[t] = (t==0)?1.f:0.f; ww_s[t] = (t==0)?1.f:0.f; }
  }
  __syncthreads();

  for (int step = 0; step < NS; ++step) {
    const int cur = step & 1;
    float* hT_cur = cur ? hT1 : hT0;
    const float* hT_prev = cur ? hT0 : hT1;

    // ================= P1: z-tile GEMM + LSTM pointwise =================
    float acc[4][4];
#pragma unroll
    for (int cc=0; cc<4; ++cc)
#pragma unroll
      for (int bb=0; bb<4; ++bb) acc[cc][bb] = 0.f;

    for (int ch = 0; ch < 10; ++ch) {
      __syncthreads();
      if (ch == 0) {               // x_t, transposed on the fly
        int sb = t >> 3, k8 = (t & 7) * 8;
        const float* src = inputs + (size_t)sb*NS*NI + (size_t)step*NI + k8;
#pragma unroll
        for (int i=0;i<8;++i) inT_s[(k8+i)*32 + sb] = src[i];
      } else if (ch == 1) {        // r (prev step)
        if (step == 0) { float4 v = make_float4(0.01f,0.01f,0.01f,0.01f);
          ((float4*)inT_s)[2*t] = v; ((float4*)inT_s)[2*t+1] = v; }
        else { ((float4*)inT_s)[2*t] = ((const float4*)rT)[2*t];
               ((float4*)inT_s)[2*t+1] = ((const float4*)rT)[2*t+1]; }
      } else {                     // h (prev step)
        if (step == 0) { float4 v = make_float4(0.f,0.f,0.f,0.f);
          ((float4*)inT_s)[2*t] = v; ((float4*)inT_s)[2*t+1] = v; }
        else { const float4* src = (const float4*)(hT_prev + (ch-2)*64*32);
          ((float4*)inT_s)[2*t] = src[2*t]; ((float4*)inT_s)[2*t+1] = src[2*t+1]; }
      }
      __syncthreads();
      const float* Wp = W_lstm + (size_t)(ch*64 + kp*16)*ZD + colg;
#pragma unroll
      for (int kk=0; kk<16; ++kk) {
        float4 av = *(const float4*)&inT_s[(kp*16+kk)*32 + b0];
        float4 wv = *(const float4*)(Wp + (size_t)kk*ZD);
        float aarr[4] = {av.x, av.y, av.z, av.w};
        float warr[4] = {wv.x, wv.y, wv.z, wv.w};
#pragma unroll
        for (int cc=0; cc<4; ++cc)
#pragma unroll
          for (int bb=0; bb<4; ++bb)
            acc[cc][bb] = fmaf(warr[cc], aarr[bb], acc[cc][bb]);
      }
    }
    __syncthreads();
#pragma unroll
    for (int cc=0; cc<4; ++cc)
      *(float4*)&zpart[(kp*32 + gate*8 + jj4 + cc)*32 + b0] =
          make_float4(acc[cc][0], acc[cc][1], acc[cc][2], acc[cc][3]);
    __syncthreads();
    {
      float zv[4];
#pragma unroll
      for (int gt=0; gt<4; ++gt) {
        int cl = gt*8 + pj;
        float s = zpart[cl*32 + pb] + zpart[1024 + cl*32 + pb]
                + zpart[2048 + cl*32 + pb] + zpart[3072 + cl*32 + pb];
        zv[gt] = s + b_lstm[gt*NH + j0 + pj];
      }
      float cn = sigm(zv[1])*c_reg + sigm(zv[0])*tanhf(zv[2]);
      c_reg = cn;
      hT_cur[(j0+pj)*32 + pb] = sigm(zv[3])*tanhf(cn);
    }

    grid.sync();

    // ================= P3': per-batch NTM chain (blocks 0..31) =================
    if (isB) {
      for (int k = t; k < NH; k += TPB) h_s[k] = hT_cur[k*32 + b];
      __syncthreads();
      // p = h @ W_int + b_int   (coalesced native-layout W reads)
      for (int c = t; c < PD; c += TPB) {
        float pacc = b_int[c];
#pragma unroll 8
        for (int k = 0; k < NH; ++k)
          pacc = fmaf(h_s[k], W_int[(size_t)k*PD + c], pacc);
        p_s[c] = pacc;
      }
      __syncthreads();
      // head params
      if (t < NM) {
        float rk = tanhf(p_s[t]);
        float wk = tanhf(p_s[70+t]);
        rk_s[t] = rk; wk_s[t] = wk;
        e_s[t] = sigm(p_s[140+t]);
        a_s[t] = tanhf(p_s[204+t]);
        float sr = rk*rk, sw = wk*wk;
#pragma unroll
        for (int off=32; off; off>>=1){ sr += __shfl_xor(sr,off); sw += __shfl_xor(sw,off); }
        if (t == 0) { scal_s[0] = sqrtf(sr); scal_s[7] = sqrtf(sw); }
      }
      if (t == 64) {
        scal_s[1] = softplus_(p_s[64]);
        scal_s[2] = sigm(p_s[65]);
        float a0=p_s[66], a1=p_s[67], a2=p_s[68];
        float m = fmaxf(a0,fmaxf(a1,a2));
        float e0=expf(a0-m), e1=expf(a1-m), e2=expf(a2-m);
        float s = e0+e1+e2;
        scal_s[3]=e0/s; scal_s[4]=e1/s; scal_s[5]=e2/s;
        scal_s[6] = 1.f + softplus_(p_s[69]);
      }
      if (t == 128) {
        scal_s[8]  = softplus_(p_s[134]);
        scal_s[9]  = sigm(p_s[135]);
        float a0=p_s[136], a1=p_s[137], a2=p_s[138];
        float m = fmaxf(a0,fmaxf(a1,a2));
        float e0=expf(a0-m), e1=expf(a1-m), e2=expf(a2-m);
        float s = e0+e1+e2;
        scal_s[10]=e0/s; scal_s[11]=e1/s; scal_s[12]=e2/s;
        scal_s[13] = 1.f + softplus_(p_s[139]);
      }
      __syncthreads();

      // write addressing (old memory)
      address_head2(t, wk_s, &scal_s[7], ww_s, mem_s, sim_s);

      // erase + add
      {
        int n = t >> 1, mh = (t & 1) * 32;
        int cn = (n & 7) << 2;
        float w = ww_s[n];
#pragma unroll
        for (int i=0;i<32;i+=4) {
          int m = mh + i;
          float* mp = &mem_s[n*NM + (m ^ cn)];
          float4 mv = *(float4*)mp;
          float4 ev = *(const float4*)&e_s[m];
          float4 av = *(const float4*)&a_s[m];
          mv.x = mv.x*(1.f - w*ev.x) + w*av.x;
          mv.y = mv.y*(1.f - w*ev.y) + w*av.y;
          mv.z = mv.z*(1.f - w*ev.z) + w*av.z;
          mv.w = mv.w*(1.f - w*ev.w) + w*av.w;
          *(float4*)mp = mv;
        }
      }
      __syncthreads();

      // read addressing (updated memory)
      address_head2(t, rk_s, &scal_s[0], wr_s, mem_s, sim_s);

      // r = w_r @ mem
      {
        int part = t >> 6, m = t & 63;
        float racc = 0.f;
#pragma unroll
        for (int nn=0; nn<32; ++nn) {
          int n = part*32 + nn;
          racc = fmaf(wr_s[n], mem_s[n*NM + (m ^ ((n&7)<<2))], racc);
        }
        red_s[part*64 + m] = racc;
      }
      __syncthreads();
      if (t < NM) {
        float rv = red_s[t] + red_s[64+t] + red_s[128+t] + red_s[192+t];
        r_s[t] = rv;
        rT[t*32 + b] = rv;
      }
      __syncthreads();

      // out = [h, r] @ W_out + b_out
      {
        int part = t >> 6, c = t & 63;
        float oacc = 0.f;
        int k0 = part*144;
#pragma unroll 4
        for (int kk=0; kk<144; ++kk) {
          int k = k0 + kk;
          float v = (k < NH) ? h_s[k] : r_s[k-NH];
          oacc = fmaf(v, W_out[(size_t)k*NO + c], oacc);
        }
        red_s[part*64 + c] = oacc;
      }
      __syncthreads();
      if (t < NO)
        out[(size_t)b*NS*NO + (size_t)step*NO + t] =
            b_out[t] + red_s[t] + red_s[64+t] + red_s[128+t] + red_s[192+t];
    }

    grid.sync();
  }
}

extern "C" void kernel_launch(void* const* d_in, const int* in_sizes, int n_in,
                              void* d_out, int out_size, void* d_ws, size_t ws_size,
                              hipStream_t stream) {
  const float* inputs = (const float*)d_in[0];
  const float* W_lstm = (const float*)d_in[1];
  const float* b_lstm = (const float*)d_in[2];
  const float* W_int  = (const float*)d_in[3];
  const float* b_int  = (const float*)d_in[4];
  const float* W_out  = (const float*)d_in[5];
  const float* b_out  = (const float*)d_in[6];
  float* outp = (float*)d_out;
  float* wsp  = (float*)d_ws;

  void* args[] = { (void*)&inputs, (void*)&W_lstm, (void*)&b_lstm,
                   (void*)&W_int, (void*)&b_int, (void*)&W_out, (void*)&b_out,
                   (void*)&outp, (void*)&wsp };
  hipLaunchCooperativeKernel((const void*)ntm_coop, dim3(GBLK), dim3(TPB),
                             args, 0, stream);
}